// Round 2
// baseline (279.516 us; speedup 1.0000x reference)
//
#include <hip/hip_runtime.h>

#define IMG_H 512
#define IMG_W 512
#define NPLANES 48          // 16 batch * 3 channels
#define TW 128              // output cols per block
#define TY 8                // output rows per block
#define VW (TW + 10)        // 138 vertical-conv columns (with x-halo)
#define VS4 139             // LDS row stride for V4 (odd: conflict-free phases)
#define VS1 139             // LDS row stride for V1
#define SSIM_C1 0.0001f     // 0.01^2
#define SSIM_C2 0.0009f     // 0.03^2

// Vertical-first separable 11x11 Gaussian conv (5 fused channels) + SSIM +
// per-block partial sum. Vertical pass: thread-per-column, 8 row-accumulators
// per channel in registers, each input pixel loaded once. Horizontal pass:
// 4 outputs/thread register-blocked, LDS reads batched as float4.
__global__ __launch_bounds__(256, 6) void ssim_tile_kernel(
    const float* __restrict__ pred, const float* __restrict__ target,
    const float* __restrict__ window, float* __restrict__ partial)
{
    __shared__ float gS[16];
    __shared__ float4 V4[TY][VS4];   // vertical conv of (p, t, p*p, t*t)
    __shared__ float  V1[TY][VS1];   // vertical conv of p*t
    __shared__ float wsum[4];

    const int tid = threadIdx.x;

    // 1D gaussian = row sums of the 2D window (normalized => row sum = g[i])
    if (tid < 11) {
        float s = 0.f;
        #pragma unroll
        for (int j = 0; j < 11; ++j) s += window[tid * 11 + j];
        gS[tid] = s;
    }
    __syncthreads();

    float g[11];
    #pragma unroll
    for (int i = 0; i < 11; ++i) g[i] = gS[i];

    const int plane = blockIdx.z;
    const int ty0 = blockIdx.y * TY;
    const int tx0 = blockIdx.x * TW;
    const float* pp = pred   + (size_t)plane * (IMG_H * IMG_W);
    const float* tp = target + (size_t)plane * (IMG_H * IMG_W);

    // ---- Vertical pass: threads 0..137 each own one padded column ----
    if (tid < VW) {
        const int gx = tx0 + tid - 5;
        const bool xok = (gx >= 0) && (gx < IMG_W);
        float am1[TY], am2[TY], a11[TY], a22[TY], a12[TY];
        #pragma unroll
        for (int o = 0; o < TY; ++o) {
            am1[o] = 0.f; am2[o] = 0.f; a11[o] = 0.f; a22[o] = 0.f; a12[o] = 0.f;
        }
        #pragma unroll
        for (int r = 0; r < TY + 10; ++r) {
            const int gy = ty0 + r - 5;
            float p = 0.f, t = 0.f;
            if (xok && gy >= 0 && gy < IMG_H) {
                p = pp[gy * IMG_W + gx];
                t = tp[gy * IMG_W + gx];
            }
            const float p2 = p * p, t2 = t * t, pt = p * t;
            #pragma unroll
            for (int o = 0; o < TY; ++o) {
                const int k = r - o;            // compile-time after unroll
                if (k >= 0 && k < 11) {
                    const float w = g[k];
                    am1[o] = fmaf(w, p,  am1[o]);
                    am2[o] = fmaf(w, t,  am2[o]);
                    a11[o] = fmaf(w, p2, a11[o]);
                    a22[o] = fmaf(w, t2, a22[o]);
                    a12[o] = fmaf(w, pt, a12[o]);
                }
            }
        }
        #pragma unroll
        for (int o = 0; o < TY; ++o) {
            V4[o][tid] = make_float4(am1[o], am2[o], a11[o], a22[o]);
            V1[o][tid] = a12[o];
        }
    }
    __syncthreads();

    // ---- Horizontal pass + SSIM: thread = (colgroup, row), 4 outputs ----
    const int cg  = tid >> 3;        // 0..31
    const int row = tid & 7;         // 0..7
    const int c0  = cg * 4;          // output col within tile
    float m1[4], m2[4], e11[4], e22[4], e12[4];
    #pragma unroll
    for (int o = 0; o < 4; ++o) {
        m1[o] = 0.f; m2[o] = 0.f; e11[o] = 0.f; e22[o] = 0.f; e12[o] = 0.f;
    }
    #pragma unroll
    for (int j = 0; j < 14; ++j) {
        const float4 v4 = V4[row][c0 + j];
        const float  v1 = V1[row][c0 + j];
        #pragma unroll
        for (int o = 0; o < 4; ++o) {
            const int k = j - o;                // compile-time after unroll
            if (k >= 0 && k < 11) {
                const float w = g[k];
                m1[o]  = fmaf(w, v4.x, m1[o]);
                m2[o]  = fmaf(w, v4.y, m2[o]);
                e11[o] = fmaf(w, v4.z, e11[o]);
                e22[o] = fmaf(w, v4.w, e22[o]);
                e12[o] = fmaf(w, v1,   e12[o]);
            }
        }
    }

    float acc = 0.f;
    #pragma unroll
    for (int o = 0; o < 4; ++o) {
        const float mu1 = m1[o], mu2 = m2[o];
        const float mu1_sq = mu1 * mu1, mu2_sq = mu2 * mu2, mu1_mu2 = mu1 * mu2;
        const float s1  = e11[o] - mu1_sq;
        const float s2  = e22[o] - mu2_sq;
        const float s12 = e12[o] - mu1_mu2;
        const float num = (2.f * mu1_mu2 + SSIM_C1) * (2.f * s12 + SSIM_C2);
        const float den = (mu1_sq + mu2_sq + SSIM_C1) * (s1 + s2 + SSIM_C2);
        acc += num / den;
    }

    // Block reduction
    #pragma unroll
    for (int off = 32; off > 0; off >>= 1)
        acc += __shfl_down(acc, off, 64);
    if ((tid & 63) == 0) wsum[tid >> 6] = acc;
    __syncthreads();
    if (tid == 0) {
        const int bid = blockIdx.x + gridDim.x * (blockIdx.y + gridDim.y * blockIdx.z);
        partial[bid] = wsum[0] + wsum[1] + wsum[2] + wsum[3];
    }
}

// Reduce 12288 partials -> scalar (1024 threads, float4 loads, double accum)
__global__ __launch_bounds__(1024) void ssim_reduce_kernel(
    const float4* __restrict__ partial4, float* __restrict__ out)
{
    float s = 0.f;
    #pragma unroll
    for (int i = 0; i < 3; ++i) {
        const float4 v = partial4[threadIdx.x + i * 1024];
        s += (v.x + v.y) + (v.z + v.w);
    }
    double acc = (double)s;
    #pragma unroll
    for (int off = 32; off > 0; off >>= 1)
        acc += __shfl_down(acc, off, 64);
    __shared__ double wsumd[16];
    const int lane = threadIdx.x & 63, wid = threadIdx.x >> 6;
    if (lane == 0) wsumd[wid] = acc;
    __syncthreads();
    if (threadIdx.x == 0) {
        double total = 0.0;
        #pragma unroll
        for (int w = 0; w < 16; ++w) total += wsumd[w];
        const double N = (double)NPLANES * IMG_H * IMG_W;
        out[0] = (float)(1.0 - total / N);
    }
}

extern "C" void kernel_launch(void* const* d_in, const int* in_sizes, int n_in,
                              void* d_out, int out_size, void* d_ws, size_t ws_size,
                              hipStream_t stream)
{
    const float* pred   = (const float*)d_in[0];
    const float* target = (const float*)d_in[1];
    const float* window = (const float*)d_in[2];
    float* out = (float*)d_out;
    float* partial = (float*)d_ws;   // 12288 floats = 48 KiB

    dim3 grid(IMG_W / TW, IMG_H / TY, NPLANES);   // (4, 64, 48) = 12288 blocks
    ssim_tile_kernel<<<grid, 256, 0, stream>>>(pred, target, window, partial);
    ssim_reduce_kernel<<<1, 1024, 0, stream>>>((const float4*)partial, out);
}

// Round 3
// 180.671 us; speedup vs baseline: 1.5471x; 1.5471x over previous
//
#include <hip/hip_runtime.h>

#define IMG_H 512
#define IMG_W 512
#define IMG_N (IMG_H * IMG_W)
#define NPLANES 48          // 16 batch * 3 channels
#define TX 64               // output cols per block
#define STRIP 128           // output rows per block
#define RB 16               // rows per iteration
#define RING 26             // LDS ring rows (16 new + 10 halo)
#define NITER (STRIP / RB)  // 8
#define SSIM_C1 0.0001f
#define SSIM_C2 0.0009f

// Row-streaming separable 11x11 Gaussian conv (5 fused channels) + SSIM.
// H phase: thread=(colgroup,row), 4-col register blocking, direct predicated
// float4 global loads, writes sigma-swizzled LDS ring (26 rows x 64 cols x 5ch).
// V phase: thread=(col,rowgroup), 14-tap sliding window over ring, 4 rows/thread.
__global__ __launch_bounds__(256) void ssim_stream_kernel(
    const float* __restrict__ pred, const float* __restrict__ target,
    const float* __restrict__ window, float* __restrict__ partial)
{
    __shared__ float4 V4[RING][64];   // (mu1,mu2,E11,E22) vertical-pending, 26.0 KB
    __shared__ float  V1[RING][65];   // E12 channel, 6.8 KB
    __shared__ float  gS[16];
    __shared__ float  wsum[4];

    const int tid = threadIdx.x;

    // 1D gaussian = row sums of the 2D window (normalized => row sum = g[i])
    if (tid < 11) {
        float s = 0.f;
        #pragma unroll
        for (int j = 0; j < 11; ++j) s += window[tid * 11 + j];
        gS[tid] = s;
    }
    __syncthreads();
    float g[11];
    #pragma unroll
    for (int i = 0; i < 11; ++i) g[i] = gS[i];

    const int plane = blockIdx.z;
    const int y0  = blockIdx.y * STRIP;
    const int tx0 = blockIdx.x * TX;
    const float* pp = pred   + (size_t)plane * IMG_N;
    const float* tp = target + (size_t)plane * IMG_N;

    // ---- H-phase role: colgroup (4 cols) x row ----
    const int hcg  = tid & 15;       // cols 4*hcg .. 4*hcg+3
    const int hrow = tid >> 4;       // 0..15
    int sigw[4];
    #pragma unroll
    for (int w = 0; w < 4; ++w)
        sigw[w] = ((hcg + 2 * w) & 7) | (hcg & 8) | (w << 4);

    // ---- V-phase role: col x rowgroup (4 rows) ----
    const int vcol = tid & 63;
    const int vrg  = tid >> 6;       // 0..3
    const int sigv = (((vcol >> 2) + 2 * (vcol & 3)) & 7) | ((vcol >> 2) & 8)
                   | ((vcol & 3) << 4);

    float acc = 0.f;

    // Horizontal conv for rows [hbase, hbase+nrows) (rel. to strip-5), ring
    // slots starting at sb (= hbase mod RING).
    auto do_H = [&](int hbase, int sb, int nrows) {
        if (hrow < nrows) {
            int slot = sb + hrow; if (slot >= RING) slot -= RING;
            const int gy = y0 - 5 + hbase + hrow;
            const bool rowok = (gy >= 0) && (gy < IMG_H);
            const float* prow = pp + gy * IMG_W;
            const float* trow = tp + gy * IMG_W;
            // load cols [c0-8, c0+12) as 5 aligned float4 per array
            float pf[20], tf[20];
            #pragma unroll
            for (int q = 0; q < 5; ++q) {
                const int cbase = tx0 + 4 * hcg - 8 + 4 * q;  // multiple of 4
                const bool ok = rowok && (cbase >= 0) && (cbase < IMG_W);
                float4 p4 = ok ? *(const float4*)(prow + cbase) : make_float4(0, 0, 0, 0);
                float4 t4 = ok ? *(const float4*)(trow + cbase) : make_float4(0, 0, 0, 0);
                pf[4*q+0] = p4.x; pf[4*q+1] = p4.y; pf[4*q+2] = p4.z; pf[4*q+3] = p4.w;
                tf[4*q+0] = t4.x; tf[4*q+1] = t4.y; tf[4*q+2] = t4.z; tf[4*q+3] = t4.w;
            }
            float m1[4], m2[4], e11[4], e22[4], e12[4];
            #pragma unroll
            for (int o = 0; o < 4; ++o) {
                m1[o] = 0.f; m2[o] = 0.f; e11[o] = 0.f; e22[o] = 0.f; e12[o] = 0.f;
            }
            #pragma unroll
            for (int j = 3; j <= 16; ++j) {       // f[j] = col c0-8+j
                const float p = pf[j], t = tf[j];
                const float p2 = p * p, t2 = t * t, pt = p * t;
                #pragma unroll
                for (int o = 0; o < 4; ++o) {
                    const int k = j - 3 - o;      // tap index, compile-time
                    if (k >= 0 && k < 11) {
                        const float w = g[k];
                        m1[o]  = fmaf(w, p,  m1[o]);
                        m2[o]  = fmaf(w, t,  m2[o]);
                        e11[o] = fmaf(w, p2, e11[o]);
                        e22[o] = fmaf(w, t2, e22[o]);
                        e12[o] = fmaf(w, pt, e12[o]);
                    }
                }
            }
            #pragma unroll
            for (int w = 0; w < 4; ++w) {
                V4[slot][sigw[w]] = make_float4(m1[w], m2[w], e11[w], e22[w]);
                V1[slot][sigw[w]] = e12[w];
            }
        }
    };

    // Vertical conv + SSIM for output rows [obase, obase+16); ob26 = obase%RING.
    auto do_V = [&](int ob26) {
        int s0 = ob26 + vrg * 4; if (s0 >= RING) s0 -= RING;
        float m1[4], m2[4], e11[4], e22[4], e12[4];
        #pragma unroll
        for (int j = 0; j < 4; ++j) {
            m1[j] = 0.f; m2[j] = 0.f; e11[j] = 0.f; e22[j] = 0.f; e12[j] = 0.f;
        }
        #pragma unroll
        for (int r = 0; r < 14; ++r) {
            int s = s0 + r; if (s >= RING) s -= RING;
            const float4 v4 = V4[s][sigv];
            const float  v1 = V1[s][sigv];
            #pragma unroll
            for (int j = 0; j < 4; ++j) {
                const int k = r - j;              // compile-time
                if (k >= 0 && k < 11) {
                    const float w = g[k];
                    m1[j]  = fmaf(w, v4.x, m1[j]);
                    m2[j]  = fmaf(w, v4.y, m2[j]);
                    e11[j] = fmaf(w, v4.z, e11[j]);
                    e22[j] = fmaf(w, v4.w, e22[j]);
                    e12[j] = fmaf(w, v1,   e12[j]);
                }
            }
        }
        #pragma unroll
        for (int j = 0; j < 4; ++j) {
            const float mu1 = m1[j], mu2 = m2[j];
            const float mu1_sq = mu1 * mu1, mu2_sq = mu2 * mu2, mu1_mu2 = mu1 * mu2;
            const float s1  = e11[j] - mu1_sq;
            const float s2  = e22[j] - mu2_sq;
            const float s12 = e12[j] - mu1_mu2;
            const float num = (2.f * mu1_mu2 + SSIM_C1) * (2.f * s12 + SSIM_C2);
            const float den = (mu1_sq + mu2_sq + SSIM_C1) * (s1 + s2 + SSIM_C2);
            acc += num / den;
        }
    };

    // Prologue: fill ring rows 0..25, then V for output rows 0..15
    do_H(0, 0, 16);
    __syncthreads();
    do_H(16, 16, 10);
    __syncthreads();
    do_V(0);

    int hb = 26, hs = 0;   // next H block: rows hb.., slot hs (= hb % RING)
    int ob = 16;           // next V block: slot of output-row base (mod RING)
    #pragma unroll 1
    for (int it = 1; it < NITER; ++it) {
        __syncthreads();   // ring reads of prev V done before overwriting
        do_H(hb, hs, 16);
        __syncthreads();
        do_V(ob);
        hb += 16;
        hs += 16; if (hs >= RING) hs -= RING;
        ob += 16; if (ob >= RING) ob -= RING;
    }

    // Block reduction
    #pragma unroll
    for (int off = 32; off > 0; off >>= 1)
        acc += __shfl_down(acc, off, 64);
    if ((tid & 63) == 0) wsum[tid >> 6] = acc;
    __syncthreads();
    if (tid == 0) {
        const int bid = blockIdx.x + gridDim.x * (blockIdx.y + gridDim.y * blockIdx.z);
        partial[bid] = wsum[0] + wsum[1] + wsum[2] + wsum[3];
    }
}

// Reduce 1536 partials -> scalar (double accumulate)
__global__ __launch_bounds__(512) void ssim_reduce_kernel(
    const float4* __restrict__ partial4, float* __restrict__ out)
{
    float s = 0.f;
    if (threadIdx.x < 384) {                 // 384 float4 = 1536 floats
        const float4 v = partial4[threadIdx.x];
        s = (v.x + v.y) + (v.z + v.w);
    }
    double acc = (double)s;
    #pragma unroll
    for (int off = 32; off > 0; off >>= 1)
        acc += __shfl_down(acc, off, 64);
    __shared__ double wsumd[8];
    const int lane = threadIdx.x & 63, wid = threadIdx.x >> 6;
    if (lane == 0) wsumd[wid] = acc;
    __syncthreads();
    if (threadIdx.x == 0) {
        double total = 0.0;
        #pragma unroll
        for (int w = 0; w < 8; ++w) total += wsumd[w];
        const double N = (double)NPLANES * IMG_H * IMG_W;
        out[0] = (float)(1.0 - total / N);
    }
}

extern "C" void kernel_launch(void* const* d_in, const int* in_sizes, int n_in,
                              void* d_out, int out_size, void* d_ws, size_t ws_size,
                              hipStream_t stream)
{
    const float* pred   = (const float*)d_in[0];
    const float* target = (const float*)d_in[1];
    const float* window = (const float*)d_in[2];
    float* out = (float*)d_out;
    float* partial = (float*)d_ws;   // 1536 floats = 6 KiB

    dim3 grid(IMG_W / TX, IMG_H / STRIP, NPLANES);   // (8, 4, 48) = 1536 blocks
    ssim_stream_kernel<<<grid, 256, 0, stream>>>(pred, target, window, partial);
    ssim_reduce_kernel<<<1, 512, 0, stream>>>((const float4*)partial, out);
}